// Round 2
// baseline (308.188 us; speedup 1.0000x reference)
//
#include <hip/hip_runtime.h>

#define OC    96
#define IH    224
#define IW    224
#define OHH   112
#define OWW   112
#define NIMG  16

// ---------------- K1: weight RMS renorm -> blocked layout [3][147][32] ----------------
__global__ __launch_bounds__(64) void renorm_kernel(const float* __restrict__ w,
                                                    float* __restrict__ wtb) {
    int oc = blockIdx.x;
    int l  = threadIdx.x;
    float ssq = 0.f;
    for (int k = l; k < 147; k += 64) {
        float v = w[oc * 147 + k];
        ssq += v * v;
    }
    #pragma unroll
    for (int off = 32; off > 0; off >>= 1) ssq += __shfl_xor(ssq, off, 64);
    float rms   = sqrtf(ssq * (1.0f / 147.0f));
    float scale = (rms > 0.1f) ? (0.1f / rms) : 1.0f;
    int ocb = oc >> 5, ocl = oc & 31;
    for (int k = l; k < 147; k += 64)
        wtb[((size_t)ocb * 147 + k) * 32 + ocl] = w[oc * 147 + k] * scale;
}

// ---------------- K2: 7x7 stride-2 conv, register-tiled 8 OC x 8 px per thread --------
// Block 448 thr = 7 waves. wave = ow-group (8 px), lane = (ocg:2b)(row:4b).
// Block tile: 32 OC x (56 ow x 16 oh). Patch de-interleaved even/odd cols in LDS.
#define PROWS 37          // 2*16+5 input rows per channel
#define PW    66          // floats per plane row (need 59/58; 66 -> stride 66, bank-friendly)
#define PW2   33          // float2 per plane row

__global__ __launch_bounds__(448, 4) void conv_kernel(const float* __restrict__ x,
                                                      const float* __restrict__ wtb,
                                                      const float* __restrict__ bias,
                                                      float* __restrict__ y) {
    __shared__ float2 sx2[3 * 2 * PROWS * PW2];  // [c][parity][row][33]
    __shared__ float4 wl4[147 * 8];              // [k][32 floats]

    const int tid  = threadIdx.x;
    const int wave = tid >> 6;        // 0..6 -> ow group
    const int lane = tid & 63;
    const int row  = lane & 15;       // 0..15 -> oh within tile
    const int ocg  = lane >> 4;       // 0..3  -> group of 8 OCs

    const int tw  = blockIdx.x & 1;   // 2 ow tiles
    const int th  = blockIdx.x >> 1;  // 7 oh tiles
    const int ow0 = 56 * tw, oh0 = 16 * th;
    const int ocb = blockIdx.y;       // 3 oc blocks of 32
    const int img = blockIdx.z;
    const int iw0 = 2 * ow0 - 3, ih0 = 2 * oh0 - 3;
    const float* xim = x + (size_t)img * 3 * IH * IW;
    float* sxf = (float*)sx2;
    float* wlf = (float*)wl4;

    // ---- stage input patch, de-interleaved by column parity of l = iw - iw0 ----
    for (int i = tid; i < 3 * PROWS * PW; i += 448) {
        int c   = i / (PROWS * PW);
        int rem = i - c * (PROWS * PW);
        int r   = rem / PW;
        int pc  = rem - r * PW;
        int ih  = ih0 + r;
        int iwE = iw0 + 2 * pc;
        float e = 0.f, o = 0.f;
        if ((unsigned)ih < IH) {
            const float* xr = xim + (c * IH + ih) * IW;
            if ((unsigned)iwE < IW)       e = xr[iwE];
            if ((unsigned)(iwE + 1) < IW) o = xr[iwE + 1];
        }
        sxf[((c * 2 + 0) * PROWS + r) * PW + pc] = e;
        sxf[((c * 2 + 1) * PROWS + r) * PW + pc] = o;
    }
    // ---- stage this block's 32-OC weight slice (contiguous) ----
    {
        const float* wsrc = wtb + (size_t)ocb * 147 * 32;
        for (int i = tid; i < 147 * 32; i += 448) wlf[i] = wsrc[i];
    }

    const int oc0 = ocb * 32 + ocg * 8;
    float4 b0 = *(const float4*)(bias + oc0);
    float4 b1 = *(const float4*)(bias + oc0 + 4);
    float acc[8][8];
    {
        float bv[8] = {b0.x, b0.y, b0.z, b0.w, b1.x, b1.y, b1.z, b1.w};
        #pragma unroll
        for (int o = 0; o < 8; o++)
            #pragma unroll
            for (int j = 0; j < 8; j++) acc[o][j] = bv[o];
    }
    __syncthreads();

    const int lp2 = wave * 4;  // float2 index of this wave's first pixel column

    #pragma unroll 1
    for (int c = 0; c < 3; ++c) {
        #pragma unroll 1
        for (int kh = 0; kh < 7; ++kh) {
            const int irow = 2 * row + kh;
            const float2* ep = sx2 + ((c * 2 + 0) * PROWS + irow) * PW2 + lp2;
            const float2* op = ep + PROWS * PW2;
            float xe[12], xo[12];
            #pragma unroll
            for (int t = 0; t < 6; ++t) {
                float2 v = ep[t]; xe[2 * t] = v.x; xe[2 * t + 1] = v.y;
                float2 u = op[t]; xo[2 * t] = u.x; xo[2 * t + 1] = u.y;
            }
            const float4* wp = wl4 + (c * 49 + kh * 7) * 8 + ocg * 2;
            #pragma unroll
            for (int kw = 0; kw < 7; ++kw) {
                float4 w0 = wp[kw * 8], w1 = wp[kw * 8 + 1];
                float wv[8] = {w0.x, w0.y, w0.z, w0.w, w1.x, w1.y, w1.z, w1.w};
                const int s = kw >> 1;
                #pragma unroll
                for (int o = 0; o < 8; ++o)
                    #pragma unroll
                    for (int j = 0; j < 8; ++j) {
                        float xv = (kw & 1) ? xo[j + s] : xe[j + s];
                        acc[o][j] = fmaf(xv, wv[o], acc[o][j]);
                    }
            }
        }
    }

    // ---- write 8 OC x 8 px ----
    const int oh  = oh0 + row;
    const int owb = ow0 + wave * 8;
    #pragma unroll
    for (int o = 0; o < 8; ++o) {
        float* yp = y + (((size_t)img * OC + oc0 + o) * OHH + oh) * OWW + owb;
        float4 v0 = {acc[o][0], acc[o][1], acc[o][2], acc[o][3]};
        float4 v1 = {acc[o][4], acc[o][5], acc[o][6], acc[o][7]};
        *(float4*)yp       = v0;
        *(float4*)(yp + 4) = v1;
    }
}

// ---------------- K3: fused LCN (two 5x5 boxes) + relu + 2x2 maxpool ----------------
__global__ __launch_bounds__(256) void lcn_pool_kernel(const float* __restrict__ y,
                                                       float* __restrict__ outp,
                                                       float* __restrict__ prep,
                                                       float* __restrict__ idxp) {
    __shared__ float sy[40 * 41];     // y tile + halo 4
    __shared__ float srow[40 * 37];   // horizontal 5-sum of y
    __shared__ float scent[36 * 37];  // centered (zeroed outside image)
    __shared__ float sc2r[36 * 33];   // horizontal 5-sum of centered^2
    __shared__ float spre[32 * 33];   // relu'd normalized tile
    const int tid  = threadIdx.x;
    const int tile = blockIdx.x;                // 0..15
    const int gx0 = (tile & 3) * 32;
    const int gy0 = (tile >> 2) * 32;
    const int plane = blockIdx.y;               // img*96 + ch
    const float* yp = y + (size_t)plane * (OHH * OWW);

    for (int i = tid; i < 40 * 40; i += 256) {
        int r = i / 40, c = i - r * 40;
        int gy = gy0 + r - 4, gx = gx0 + c - 4;
        float v = 0.f;
        if ((unsigned)gy < OHH && (unsigned)gx < OWW) v = yp[gy * OWW + gx];
        sy[r * 41 + c] = v;
    }
    __syncthreads();

    for (int i = tid; i < 40 * 36; i += 256) {
        int r = i / 36, cc = i - r * 36;
        const float* b = &sy[r * 41 + cc];
        srow[r * 37 + cc] = b[0] + b[1] + b[2] + b[3] + b[4];
    }
    __syncthreads();

    for (int i = tid; i < 36 * 36; i += 256) {
        int rr = i / 36, cc = i - rr * 36;
        const float* b = &srow[rr * 37 + cc];
        float m = (b[0] + b[37] + b[74] + b[111] + b[148]) * 0.04f;
        int gy = gy0 + rr - 2, gx = gx0 + cc - 2;
        float cent = 0.f;
        if ((unsigned)gy < OHH && (unsigned)gx < OWW)
            cent = sy[(rr + 2) * 41 + cc + 2] - m;   // zero outside image
        scent[rr * 37 + cc] = cent;
    }
    __syncthreads();

    for (int i = tid; i < 36 * 32; i += 256) {
        int rr = i / 32, c3 = i - rr * 32;
        const float* b = &scent[rr * 37 + c3];
        sc2r[rr * 33 + c3] = b[0]*b[0] + b[1]*b[1] + b[2]*b[2] + b[3]*b[3] + b[4]*b[4];
    }
    __syncthreads();

    for (int i = tid; i < 32 * 32; i += 256) {
        int r4 = i / 32, c3 = i - r4 * 32;
        const float* b = &sc2r[r4 * 33 + c3];
        float var  = (b[0] + b[33] + b[66] + b[99] + b[132]) * 0.04f;
        float cent = scent[(r4 + 2) * 37 + c3 + 2];
        float val  = cent * rsqrtf(var + 1.0f);
        val = fmaxf(val, 0.f);
        spre[r4 * 33 + c3] = val;
        int gy = gy0 + r4, gx = gx0 + c3;
        if (gy < OHH && gx < OWW)
            prep[(size_t)plane * (OHH * OWW) + gy * OWW + gx] = val;
    }
    __syncthreads();

    {   // 2x2 maxpool, first-max-wins argmax, torch flat index into 112x112 plane
        int hp = tid >> 4, wp = tid & 15;
        int gy = gy0 + 2 * hp, gx = gx0 + 2 * wp;
        if (gy + 1 < OHH && gx + 1 < OWW) {
            float v0 = spre[(2*hp)     * 33 + 2*wp];
            float v1 = spre[(2*hp)     * 33 + 2*wp + 1];
            float v2 = spre[(2*hp + 1) * 33 + 2*wp];
            float v3 = spre[(2*hp + 1) * 33 + 2*wp + 1];
            float best = v0; int loc = 0;
            if (v1 > best) { best = v1; loc = 1; }
            if (v2 > best) { best = v2; loc = 2; }
            if (v3 > best) { best = v3; loc = 3; }
            int oh = gy >> 1, ow = gx >> 1;
            int idx = (gy + (loc >> 1)) * OWW + (gx + (loc & 1));
            size_t oidx = (size_t)plane * (56 * 56) + oh * 56 + ow;
            outp[oidx] = best;
            idxp[oidx] = (float)idx;
        }
    }
}

extern "C" void kernel_launch(void* const* d_in, const int* in_sizes, int n_in,
                              void* d_out, int out_size, void* d_ws, size_t ws_size,
                              hipStream_t stream) {
    const float* x    = (const float*)d_in[0];
    const float* w    = (const float*)d_in[1];
    const float* bias = (const float*)d_in[2];

    float* y   = (float*)d_ws;                                  // 19,267,584 f32
    float* wtb = y + (size_t)NIMG * OC * OHH * OWW;             // 14,112 f32

    float* outp = (float*)d_out;                                // [16,96,56,56]
    float* prep = outp + (size_t)NIMG * OC * 56 * 56;           // [16,96,112,112]
    float* idxp = prep + (size_t)NIMG * OC * OHH * OWW;         // [16,96,56,56]

    renorm_kernel<<<dim3(OC), dim3(64), 0, stream>>>(w, wtb);
    conv_kernel<<<dim3(14, 3, NIMG), dim3(448), 0, stream>>>(x, wtb, bias, y);
    lcn_pool_kernel<<<dim3(16, NIMG * OC), dim3(256), 0, stream>>>(y, outp, prep, idxp);
}

// Round 3
// 206.887 us; speedup vs baseline: 1.4896x; 1.4896x over previous
//
#include <hip/hip_runtime.h>

#define OC    96
#define IH    224
#define IW    224
#define OHH   112
#define OWW   112
#define NIMG  16

// ---------------- K1: weight RMS renorm -> blocked layout [3][147][32] ----------------
__global__ __launch_bounds__(64) void renorm_kernel(const float* __restrict__ w,
                                                    float* __restrict__ wtb) {
    int oc = blockIdx.x;
    int l  = threadIdx.x;
    float ssq = 0.f;
    for (int k = l; k < 147; k += 64) {
        float v = w[oc * 147 + k];
        ssq += v * v;
    }
    #pragma unroll
    for (int off = 32; off > 0; off >>= 1) ssq += __shfl_xor(ssq, off, 64);
    float rms   = sqrtf(ssq * (1.0f / 147.0f));
    float scale = (rms > 0.1f) ? (0.1f / rms) : 1.0f;
    int ocb = oc >> 5, ocl = oc & 31;
    for (int k = l; k < 147; k += 64)
        wtb[((size_t)ocb * 147 + k) * 32 + ocl] = w[oc * 147 + k] * scale;
}

// ---------------- K2: 7x7 stride-2 conv, 8 OC x 8 px per thread, 256-thr blocks -------
// Block tile: 32 OC x (32 ow x 16 oh). 4 waves; wave = ow-group of 8; lane=(ocg:2)(row:4).
// Input patch de-interleaved by column parity in LDS; PW=38 stride (2-way-free banks).
#define PROWS 37
#define PW    38
#define PW2   19

__global__ __launch_bounds__(256, 2) void conv_kernel(const float* __restrict__ x,
                                                      const float* __restrict__ wtb,
                                                      const float* __restrict__ bias,
                                                      float* __restrict__ y) {
    __shared__ float2 sx2[3 * 2 * PROWS * PW2];   // 33.7 KB
    __shared__ float4 wl4[147 * 8];               // 18.8 KB
    float* sxf = (float*)sx2;

    const int tid  = threadIdx.x;
    const int wave = tid >> 6;        // 0..3 -> ow group of 8
    const int lane = tid & 63;
    const int row  = lane & 15;       // oh within tile
    const int ocg  = lane >> 4;       // group of 8 OCs

    const int tw  = blockIdx.x & 3;   // 4 ow tiles (last covers 96..111 only)
    const int th  = blockIdx.x >> 2;  // 7 oh tiles
    const int ow0 = 32 * tw, oh0 = 16 * th;
    const int ocb = blockIdx.y;
    const int img = blockIdx.z;
    const int iw0 = 2 * ow0 - 3, ih0 = 2 * oh0 - 3;
    const float* xim = x + (size_t)img * 3 * IH * IW;

    // ---- stage input patch (each thread loads a consecutive float pair) ----
    for (int i = tid; i < 3 * PROWS * 35; i += 256) {
        int c   = i / (PROWS * 35);
        int rem = i - c * (PROWS * 35);
        int r   = rem / 35;
        int pc  = rem - r * 35;
        int ih  = ih0 + r;
        int iwE = iw0 + 2 * pc;
        float e = 0.f, o = 0.f;
        if ((unsigned)ih < IH) {
            const float* xr = xim + (c * IH + ih) * IW;
            if ((unsigned)iwE < IW)       e = xr[iwE];
            if ((unsigned)(iwE + 1) < IW) o = xr[iwE + 1];
        }
        sxf[((c * 2 + 0) * PROWS + r) * PW + pc] = e;
        sxf[((c * 2 + 1) * PROWS + r) * PW + pc] = o;
    }
    // ---- stage 32-OC weight slice as float4 ----
    {
        const float4* wsrc = (const float4*)(wtb + (size_t)ocb * 147 * 32);
        for (int i = tid; i < 147 * 8; i += 256) wl4[i] = wsrc[i];
    }

    const int oc0 = ocb * 32 + ocg * 8;
    float4 b0 = *(const float4*)(bias + oc0);
    float4 b1 = *(const float4*)(bias + oc0 + 4);
    float acc[8][8];
    {
        float bv[8] = {b0.x, b0.y, b0.z, b0.w, b1.x, b1.y, b1.z, b1.w};
        #pragma unroll
        for (int o = 0; o < 8; o++)
            #pragma unroll
            for (int j = 0; j < 8; j++) acc[o][j] = bv[o];
    }
    __syncthreads();

    const int lp2 = wave * 4;   // float2 index of this wave's first even/odd column

    #pragma unroll 1
    for (int c = 0; c < 3; ++c) {
        #pragma unroll 1
        for (int kh = 0; kh < 7; ++kh) {
            const int irow = 2 * row + kh;
            const float2* ep = sx2 + ((c * 2 + 0) * PROWS + irow) * PW2 + lp2;
            const float2* op = ep + PROWS * PW2;
            float xe[12], xo[10];
            #pragma unroll
            for (int t = 0; t < 6; ++t) { float2 v = ep[t]; xe[2*t] = v.x; xe[2*t+1] = v.y; }
            #pragma unroll
            for (int t = 0; t < 5; ++t) { float2 u = op[t]; xo[2*t] = u.x; xo[2*t+1] = u.y; }
            const float4* wp = wl4 + (c * 49 + kh * 7) * 8 + ocg * 2;
            #pragma unroll
            for (int kw = 0; kw < 7; ++kw) {
                float4 w0 = wp[kw * 8], w1 = wp[kw * 8 + 1];
                float wv[8] = {w0.x, w0.y, w0.z, w0.w, w1.x, w1.y, w1.z, w1.w};
                const int s = kw >> 1;
                #pragma unroll
                for (int o = 0; o < 8; ++o)
                    #pragma unroll
                    for (int j = 0; j < 8; ++j) {
                        float xv = (kw & 1) ? xo[j + s] : xe[j + s];
                        acc[o][j] = fmaf(xv, wv[o], acc[o][j]);
                    }
            }
        }
    }

    // ---- write 8 OC x 8 px (wave-uniform guard for the partial ow tile) ----
    const int oh  = oh0 + row;
    const int owb = ow0 + wave * 8;
    if (owb < OWW) {
        #pragma unroll
        for (int o = 0; o < 8; ++o) {
            float* yp = y + (((size_t)img * OC + oc0 + o) * OHH + oh) * OWW + owb;
            float4 v0 = {acc[o][0], acc[o][1], acc[o][2], acc[o][3]};
            float4 v1 = {acc[o][4], acc[o][5], acc[o][6], acc[o][7]};
            *(float4*)yp       = v0;
            *(float4*)(yp + 4) = v1;
        }
    }
}

// ---------------- K3: fused LCN + relu + 2x2 maxpool, 56x56 tiles, aliased LDS --------
__global__ __launch_bounds__(256) void lcn_pool_kernel(const float* __restrict__ y,
                                                       float* __restrict__ outp,
                                                       float* __restrict__ prep,
                                                       float* __restrict__ idxp) {
    __shared__ float sm[11724];                 // 46.9 KB total
    float* sy   = sm;                           // [64][65]
    float* srow = sm + 4160;                    // [64][61] horizontal 5-sum of y
    float* sc   = sm + 8064;                    // [60][61] centered
    float* sq   = srow;                         // [60][57] horiz 5-sum of centered^2 (aliases srow)
    float* spre = sy;                           // [56][57] relu'd normalized (aliases sy)

    const int tid = threadIdx.x;
    const int gx0 = (blockIdx.x & 1) * 56;
    const int gy0 = (blockIdx.x >> 1) * 56;
    const int plane = blockIdx.y;               // img*96 + ch
    const float* yp = y + (size_t)plane * (OHH * OWW);

    for (int i = tid; i < 64 * 64; i += 256) {
        int r = i >> 6, c = i & 63;
        int gy = gy0 + r - 4, gx = gx0 + c - 4;
        float v = 0.f;
        if ((unsigned)gy < OHH && (unsigned)gx < OWW) v = yp[gy * OWW + gx];
        sy[r * 65 + c] = v;
    }
    __syncthreads();

    for (int i = tid; i < 64 * 60; i += 256) {
        int r = i / 60, h = i - r * 60;
        const float* b = &sy[r * 65 + h];
        srow[r * 61 + h] = b[0] + b[1] + b[2] + b[3] + b[4];
    }
    __syncthreads();

    for (int i = tid; i < 60 * 60; i += 256) {
        int rr = i / 60, h = i - rr * 60;
        const float* b = &srow[rr * 61 + h];
        float m = (b[0] + b[61] + b[122] + b[183] + b[244]) * 0.04f;
        int gy = gy0 + rr - 2, gx = gx0 + h - 2;
        float cent = 0.f;
        if ((unsigned)gy < OHH && (unsigned)gx < OWW)
            cent = sy[(rr + 2) * 65 + (h + 2)] - m;   // zero outside image
        sc[rr * 61 + h] = cent;
    }
    __syncthreads();

    for (int i = tid; i < 60 * 56; i += 256) {
        int rr = i / 56, c = i - rr * 56;
        const float* b = &sc[rr * 61 + c];
        sq[rr * 57 + c] = b[0]*b[0] + b[1]*b[1] + b[2]*b[2] + b[3]*b[3] + b[4]*b[4];
    }
    __syncthreads();

    for (int i = tid; i < 56 * 56; i += 256) {
        int r = i / 56, c = i - r * 56;
        const float* b = &sq[r * 57 + c];
        float var  = (b[0] + b[57] + b[114] + b[171] + b[228]) * 0.04f;
        float cent = sc[(r + 2) * 61 + (c + 2)];
        float val  = fmaxf(cent * rsqrtf(var + 1.0f), 0.f);
        spre[r * 57 + c] = val;
        prep[(size_t)plane * (OHH * OWW) + (gy0 + r) * OWW + gx0 + c] = val;
    }
    __syncthreads();

    for (int i = tid; i < 28 * 28; i += 256) {
        int hp = i / 28, wp = i - hp * 28;
        float v0 = spre[(2*hp)     * 57 + 2*wp];
        float v1 = spre[(2*hp)     * 57 + 2*wp + 1];
        float v2 = spre[(2*hp + 1) * 57 + 2*wp];
        float v3 = spre[(2*hp + 1) * 57 + 2*wp + 1];
        float best = v0; int loc = 0;
        if (v1 > best) { best = v1; loc = 1; }
        if (v2 > best) { best = v2; loc = 2; }
        if (v3 > best) { best = v3; loc = 3; }
        int gy = gy0 + 2 * hp, gx = gx0 + 2 * wp;
        int idx = (gy + (loc >> 1)) * OWW + (gx + (loc & 1));
        size_t oidx = (size_t)plane * (56 * 56) + (gy >> 1) * 56 + (gx >> 1);
        outp[oidx] = best;
        idxp[oidx] = (float)idx;
    }
}

extern "C" void kernel_launch(void* const* d_in, const int* in_sizes, int n_in,
                              void* d_out, int out_size, void* d_ws, size_t ws_size,
                              hipStream_t stream) {
    const float* x    = (const float*)d_in[0];
    const float* w    = (const float*)d_in[1];
    const float* bias = (const float*)d_in[2];

    float* y   = (float*)d_ws;                                  // 19,267,584 f32
    float* wtb = y + (size_t)NIMG * OC * OHH * OWW;             // 14,112 f32

    float* outp = (float*)d_out;                                // [16,96,56,56]
    float* prep = outp + (size_t)NIMG * OC * 56 * 56;           // [16,96,112,112]
    float* idxp = prep + (size_t)NIMG * OC * OHH * OWW;         // [16,96,56,56]

    renorm_kernel<<<dim3(OC), dim3(64), 0, stream>>>(w, wtb);
    conv_kernel<<<dim3(28, 3, NIMG), dim3(256), 0, stream>>>(x, wtb, bias, y);
    lcn_pool_kernel<<<dim3(4, NIMG * OC), dim3(256), 0, stream>>>(y, outp, prep, idxp);
}

// Round 4
// 126.331 us; speedup vs baseline: 2.4395x; 1.6377x over previous
//
#include <hip/hip_runtime.h>

#define OC    96
#define IH    224
#define IW    224
#define OHH   112
#define OWW   112
#define NIMG  16

// ---------------- K1: weight RMS renorm -> layout [oc/8][c][kh][kw][8] ----------------
__global__ __launch_bounds__(64) void renorm_kernel(const float* __restrict__ w,
                                                    float* __restrict__ wtb2) {
    int oc = blockIdx.x;
    int l  = threadIdx.x;
    float ssq = 0.f;
    for (int k = l; k < 147; k += 64) {
        float v = w[oc * 147 + k];
        ssq += v * v;
    }
    #pragma unroll
    for (int off = 32; off > 0; off >>= 1) ssq += __shfl_xor(ssq, off, 64);
    float rms   = sqrtf(ssq * (1.0f / 147.0f));
    float scale = (rms > 0.1f) ? (0.1f / rms) : 1.0f;
    int g = oc >> 3, ol = oc & 7;
    for (int k = l; k < 147; k += 64)
        wtb2[((size_t)g * 147 + k) * 8 + ol] = w[oc * 147 + k] * scale;
}

// ---------------- K2: 7x7 stride-2 conv, weights via wave-uniform scalar loads --------
// Block tile: 32 OC x (32 ow x 16 oh). 4 waves; wave = 8-OC group (uniform);
// lane = (owg:2b)(row:4b) -> 8 px per thread, 8 OC x 8 px accumulators.
// LDS holds only the input patch, de-interleaved by column parity.
#define PROWS 37
#define PW    38
#define PW2   19

__global__ __launch_bounds__(256, 4) void conv_kernel(const float* __restrict__ x,
                                                      const float* __restrict__ wtb2,
                                                      const float* __restrict__ bias,
                                                      float* __restrict__ y) {
    __shared__ float2 sx2[3 * 2 * PROWS * PW2];   // 33.7 KB
    float* sxf = (float*)sx2;

    const int tid  = threadIdx.x;
    const int wave = tid >> 6;        // 0..3 -> 8-OC group
    const int lane = tid & 63;
    const int row  = lane & 15;       // oh within tile
    const int owg  = lane >> 4;       // ow group of 8

    const int tw  = blockIdx.x & 3;   // 4 ow tiles (last partially used)
    const int th  = blockIdx.x >> 2;  // 7 oh tiles
    const int ow0 = 32 * tw, oh0 = 16 * th;
    const int ocb = blockIdx.y;
    const int img = blockIdx.z;
    const int iw0 = 2 * ow0 - 3, ih0 = 2 * oh0 - 3;
    const float* xim = x + (size_t)img * 3 * IH * IW;

    // wave-uniform weight-group index (forces SGPR -> scalar loads)
    const int wg = __builtin_amdgcn_readfirstlane(ocb * 4 + wave);

    // ---- stage input patch, de-interleaved by column parity ----
    for (int i = tid; i < 3 * PROWS * 35; i += 256) {
        int c   = i / (PROWS * 35);
        int rem = i - c * (PROWS * 35);
        int r   = rem / 35;
        int pc  = rem - r * 35;
        int ih  = ih0 + r;
        int iwE = iw0 + 2 * pc;
        float e = 0.f, o = 0.f;
        if ((unsigned)ih < IH) {
            const float* xr = xim + (c * IH + ih) * IW;
            if ((unsigned)iwE < IW)       e = xr[iwE];
            if ((unsigned)(iwE + 1) < IW) o = xr[iwE + 1];
        }
        sxf[((c * 2 + 0) * PROWS + r) * PW + pc] = e;
        sxf[((c * 2 + 1) * PROWS + r) * PW + pc] = o;
    }

    const int oc0 = wg * 8;
    float4 b0 = *(const float4*)(bias + oc0);
    float4 b1 = *(const float4*)(bias + oc0 + 4);
    float acc[8][8];
    {
        float bv[8] = {b0.x, b0.y, b0.z, b0.w, b1.x, b1.y, b1.z, b1.w};
        #pragma unroll
        for (int o = 0; o < 8; o++)
            #pragma unroll
            for (int j = 0; j < 8; j++) acc[o][j] = bv[o];
    }
    __syncthreads();

    const int lp2 = owg * 4;   // float2 index of this thread's first even/odd column

    #pragma unroll 1
    for (int c = 0; c < 3; ++c) {
        #pragma unroll 1
        for (int kh = 0; kh < 7; ++kh) {
            const int irow = 2 * row + kh;
            const float2* ep = sx2 + ((c * 2 + 0) * PROWS + irow) * PW2 + lp2;
            const float2* op = ep + PROWS * PW2;
            float xe[12], xo[10];
            #pragma unroll
            for (int t = 0; t < 6; ++t) { float2 v = ep[t]; xe[2*t] = v.x; xe[2*t+1] = v.y; }
            #pragma unroll
            for (int t = 0; t < 5; ++t) { float2 u = op[t]; xo[2*t] = u.x; xo[2*t+1] = u.y; }
            // 56 wave-uniform weights for this (c,kh): [kw][8oc]
            const float* wq = wtb2 + (((size_t)wg * 3 + c) * 7 + kh) * 56;
            #pragma unroll
            for (int kw = 0; kw < 7; ++kw) {
                const int s = kw >> 1;
                #pragma unroll
                for (int o = 0; o < 8; ++o) {
                    float wv = wq[kw * 8 + o];
                    #pragma unroll
                    for (int j = 0; j < 8; ++j) {
                        float xv = (kw & 1) ? xo[j + s] : xe[j + s];
                        acc[o][j] = fmaf(xv, wv, acc[o][j]);
                    }
                }
            }
        }
    }

    // ---- write 8 OC x 8 px ----
    const int oh  = oh0 + row;
    const int owb = ow0 + owg * 8;
    if (owb < OWW) {
        #pragma unroll
        for (int o = 0; o < 8; ++o) {
            float* yp = y + (((size_t)img * OC + oc0 + o) * OHH + oh) * OWW + owb;
            float4 v0 = {acc[o][0], acc[o][1], acc[o][2], acc[o][3]};
            float4 v1 = {acc[o][4], acc[o][5], acc[o][6], acc[o][7]};
            *(float4*)yp       = v0;
            *(float4*)(yp + 4) = v1;
        }
    }
}

// ---------------- K3: LDS-free fused LCN + relu + maxpool (shuffle + reg rings) -------
// Block = 4 waves; wave w handles 28-row band of one plane. Lane owns cols 2l,2l+1.
// Horizontal 5-taps via lane shuffles (lanes 56..63 are zero -> free edge handling);
// vertical 5-taps via register ring buffers. Zero LDS, zero barriers.
__global__ __launch_bounds__(256) void lcn_pool_kernel(const float* __restrict__ y,
                                                       float* __restrict__ outp,
                                                       float* __restrict__ prep,
                                                       float* __restrict__ idxp) {
    const int tid   = threadIdx.x;
    const int band  = tid >> 6;
    const int lane  = tid & 63;
    const int plane = blockIdx.x;
    const int r0    = band * 28;
    const int c0    = lane * 2;
    const bool colv = (lane < 56);

    const float* yp = y + (size_t)plane * (OHH * OWW);
    float*      pp  = prep + (size_t)plane * (OHH * OWW);
    float*      op_ = outp + (size_t)plane * (56 * 56);
    float*      ip_ = idxp + (size_t)plane * (56 * 56);

    const int lm = (lane + 63) & 63;   // left neighbor (wraps to zero-lane 63)
    const int lp = (lane + 1) & 63;    // right neighbor (lane 55 -> zero-lane 56)

    float2 hs0{0,0}, hs1{0,0}, hs2{0,0}, hs3{0,0}, hs4{0,0};
    float2 q0{0,0},  q1{0,0},  q2{0,0},  q3{0,0},  q4{0,0};
    float2 y0{0,0},  y1{0,0},  y2{0,0};
    float2 ct0{0,0}, ct1{0,0}, ct2{0,0};
    float2 prev{0,0};

    #pragma unroll 1
    for (int i = 0; i < 36; ++i) {
        const int irow = r0 - 4 + i;
        float2 v = {0.f, 0.f};
        if ((unsigned)irow < OHH && colv)
            v = *(const float2*)(yp + irow * OWW + c0);

        // horizontal 5-sum of y for both columns
        float Lx = __shfl(v.x, lm, 64), Ly = __shfl(v.y, lm, 64);
        float Rx = __shfl(v.x, lp, 64), Ry = __shfl(v.y, lp, 64);
        float2 hs_new;
        hs_new.x = Lx + Ly + v.x + v.y + Rx;
        hs_new.y = Ly + v.x + v.y + Rx + Ry;
        hs0 = hs1; hs1 = hs2; hs2 = hs3; hs3 = hs4; hs4 = hs_new;
        y0 = y1; y1 = y2; y2 = v;

        if (i >= 4) {
            const int m = irow - 2;
            float2 mean;
            mean.x = (hs0.x + hs1.x + hs2.x + hs3.x + hs4.x) * 0.04f;
            mean.y = (hs0.y + hs1.y + hs2.y + hs3.y + hs4.y) * 0.04f;
            float2 ct;
            ct.x = y0.x - mean.x;
            ct.y = y0.y - mean.y;
            if ((unsigned)m >= OHH || !colv) { ct.x = 0.f; ct.y = 0.f; }

            float cLx = __shfl(ct.x, lm, 64), cLy = __shfl(ct.y, lm, 64);
            float cRx = __shfl(ct.x, lp, 64), cRy = __shfl(ct.y, lp, 64);
            float2 q_new;
            q_new.x = cLx*cLx + cLy*cLy + ct.x*ct.x + ct.y*ct.y + cRx*cRx;
            q_new.y = cLy*cLy + ct.x*ct.x + ct.y*ct.y + cRx*cRx + cRy*cRy;
            q0 = q1; q1 = q2; q2 = q3; q3 = q4; q4 = q_new;
            ct0 = ct1; ct1 = ct2; ct2 = ct;

            if (i >= 8) {
                const int o = irow - 4;   // r0 .. r0+27
                float2 var;
                var.x = (q0.x + q1.x + q2.x + q3.x + q4.x) * 0.04f;
                var.y = (q0.y + q1.y + q2.y + q3.y + q4.y) * 0.04f;
                float vx = fmaxf(ct0.x * rsqrtf(var.x + 1.0f), 0.f);
                float vy = fmaxf(ct0.y * rsqrtf(var.y + 1.0f), 0.f);
                if (colv) {
                    float2 pv = {vx, vy};
                    *(float2*)(pp + o * OWW + c0) = pv;
                }
                if (o & 1) {
                    float best = prev.x; int loc = 0;
                    if (prev.y > best) { best = prev.y; loc = 1; }
                    if (vx     > best) { best = vx;     loc = 2; }
                    if (vy     > best) { best = vy;     loc = 3; }
                    int idx = (o - 1 + (loc >> 1)) * OWW + (c0 + (loc & 1));
                    if (colv) {
                        size_t oo = (size_t)(o >> 1) * 56 + lane;
                        op_[oo] = best;
                        ip_[oo] = (float)idx;
                    }
                }
                prev.x = vx; prev.y = vy;
            }
        }
    }
}

extern "C" void kernel_launch(void* const* d_in, const int* in_sizes, int n_in,
                              void* d_out, int out_size, void* d_ws, size_t ws_size,
                              hipStream_t stream) {
    const float* x    = (const float*)d_in[0];
    const float* w    = (const float*)d_in[1];
    const float* bias = (const float*)d_in[2];

    float* y    = (float*)d_ws;                                 // 19,267,584 f32
    float* wtb2 = y + (size_t)NIMG * OC * OHH * OWW;            // 14,112 f32

    float* outp = (float*)d_out;                                // [16,96,56,56]
    float* prep = outp + (size_t)NIMG * OC * 56 * 56;           // [16,96,112,112]
    float* idxp = prep + (size_t)NIMG * OC * OHH * OWW;         // [16,96,56,56]

    renorm_kernel<<<dim3(OC), dim3(64), 0, stream>>>(w, wtb2);
    conv_kernel<<<dim3(28, 3, NIMG), dim3(256), 0, stream>>>(x, wtb2, bias, y);
    lcn_pool_kernel<<<dim3(NIMG * OC), dim3(256), 0, stream>>>(y, outp, prep, idxp);
}

// Round 5
// 78.632 us; speedup vs baseline: 3.9194x; 1.6066x over previous
//
#include <hip/hip_runtime.h>

#define OC    96
#define IH    224
#define IW    224
#define OHH   112
#define OWW   112
#define NIMG  16

typedef __attribute__((ext_vector_type(8))) short bf16x8;
typedef __attribute__((ext_vector_type(4))) float f32x4;

static __device__ inline unsigned short f2bf(float f) {
    // round-to-nearest-even bf16
    unsigned int u = __float_as_uint(f);
    unsigned int rounded = u + 0x7fff + ((u >> 16) & 1);
    return (unsigned short)(rounded >> 16);
}

// ---------------- K1: renorm + prepack weights into MFMA A-fragment order -------------
// wfrag[mt 0..5][ch 0..5][lane 0..63] = 8 bf16: A[oc=mt*16+(lane&15)][k'=ch*32+(lane>>4)*8+j]
// k' -> unit U=k'>>3 (c=U/7, kh=U%7 for U<21, else pad), kw=j (j==7 -> pad zero)
__global__ __launch_bounds__(64) void wfrag_kernel(const float* __restrict__ w,
                                                   uint4* __restrict__ wfrag) {
    const int bid = blockIdx.x;          // 36 blocks: mt*6 + ch
    const int mt = bid / 6, ch = bid - mt * 6;
    const int lane = threadIdx.x;
    const int oc = mt * 16 + (lane & 15);
    const int u  = lane >> 4;

    float ssq = 0.f;
    for (int k = 0; k < 147; ++k) {
        float v = w[oc * 147 + k];
        ssq += v * v;
    }
    float rms   = sqrtf(ssq * (1.0f / 147.0f));
    float scale = (rms > 0.1f) ? (0.1f / rms) : 1.0f;

    const int U = ch * 4 + u;
    unsigned short h[8];
    #pragma unroll
    for (int j = 0; j < 8; ++j) {
        float val = 0.f;
        if (U < 21 && j < 7) {
            int c  = U / 7;
            int kh = U - 7 * c;
            val = w[oc * 147 + c * 49 + kh * 7 + j] * scale;
        }
        h[j] = f2bf(val);
    }
    uint4 o;
    o.x = (unsigned)h[0] | ((unsigned)h[1] << 16);
    o.y = (unsigned)h[2] | ((unsigned)h[3] << 16);
    o.z = (unsigned)h[4] | ((unsigned)h[5] << 16);
    o.w = (unsigned)h[6] | ((unsigned)h[7] << 16);
    wfrag[(mt * 6 + ch) * 64 + lane] = o;
}

// ---------------- K2: 7x7 stride-2 conv via bf16 MFMA, y written as bf16 --------------
// Block 512 thr = 8 waves (2 wm x 4 wn). Tile: 96 oc x (16 ow x 8 oh).
// Wave: 48 oc (3 m-tiles) x 32 px (2 oh rows). K padded 147->192, 6 chunks of 32.
__global__ __launch_bounds__(512, 2) void conv_mfma_kernel(const float* __restrict__ x,
                                                           const uint4* __restrict__ wfrag,
                                                           const float* __restrict__ bias,
                                                           unsigned short* __restrict__ ypb) {
    __shared__ float patch[3 * 21 * 40];   // 40.3 KB, cols shifted +3 (col = iw - (2*ow0-3))

    const int tid  = threadIdx.x;
    const int bx   = blockIdx.x;           // 98 px tiles: tx = bx%7 (ow), ty = bx/7 (oh)
    const int img  = blockIdx.y;
    const int tx = bx % 7, ty = bx / 7;
    const int ow0 = 16 * tx, oh0 = 8 * ty;
    const int ih0 = 2 * oh0 - 3, iwb = 2 * ow0 - 3;
    const float* xim = x + (size_t)img * 3 * IH * IW;

    // ---- stage f32 patch [3][21][40] ----
    for (int i = tid; i < 3 * 21 * 40; i += 512) {
        int c   = i / 840;
        int rem = i - c * 840;
        int r   = rem / 40;
        int cc  = rem - r * 40;
        int ih = ih0 + r, iw = iwb + cc;
        float v = 0.f;
        if ((unsigned)ih < IH && (unsigned)iw < IW) v = xim[(c * IH + ih) * IW + iw];
        patch[i] = v;
    }

    const int wv   = tid >> 6;
    const int lane = tid & 63;
    const int wm = wv >> 2;               // 0..1 -> 48-oc half
    const int wn = wv & 3;                // 0..3 -> pair of oh rows
    const int n  = lane & 15;             // px col within n-tile (= ow offset)
    const int u  = lane >> 4;             // k-subgroup

    f32x4 acc[3][2];
    #pragma unroll
    for (int a = 0; a < 3; ++a)
        #pragma unroll
        for (int t = 0; t < 2; ++t) acc[a][t] = (f32x4){0.f, 0.f, 0.f, 0.f};

    // prefetch A-frags for chunk 0
    uint4 anxt[3];
    #pragma unroll
    for (int a = 0; a < 3; ++a)
        anxt[a] = wfrag[(((wm * 3 + a) * 6) + 0) * 64 + lane];

    __syncthreads();

    #pragma unroll
    for (int ch = 0; ch < 6; ++ch) {
        uint4 acur[3] = {anxt[0], anxt[1], anxt[2]};
        if (ch < 5) {
            #pragma unroll
            for (int a = 0; a < 3; ++a)
                anxt[a] = wfrag[(((wm * 3 + a) * 6) + ch + 1) * 64 + lane];
        }
        // unit for this lane's k-subgroup
        int U = ch * 4 + u;
        int cq = 0, khq = 0;
        if (U < 21) { cq = U / 7; khq = U - 7 * cq; }
        #pragma unroll
        for (int nt = 0; nt < 2; ++nt) {
            const int t = 2 * wn + nt;
            const float* bp = &patch[cq * 840 + (2 * t + khq) * 40 + 2 * n];
            float2 p0 = *(const float2*)(bp + 0);
            float2 p1 = *(const float2*)(bp + 2);
            float2 p2 = *(const float2*)(bp + 4);
            float2 p3 = *(const float2*)(bp + 6);
            bf16x8 bfr;
            bfr[0] = (short)f2bf(p0.x); bfr[1] = (short)f2bf(p0.y);
            bfr[2] = (short)f2bf(p1.x); bfr[3] = (short)f2bf(p1.y);
            bfr[4] = (short)f2bf(p2.x); bfr[5] = (short)f2bf(p2.y);
            bfr[6] = (short)f2bf(p3.x); bfr[7] = (short)f2bf(p3.y);
            #pragma unroll
            for (int a = 0; a < 3; ++a) {
                bf16x8 afr = *(bf16x8*)&acur[a];
                acc[a][nt] = __builtin_amdgcn_mfma_f32_16x16x32_bf16(afr, bfr, acc[a][nt], 0, 0, 0);
            }
        }
    }

    // ---- epilogue: bias + bf16 store ----
    #pragma unroll
    for (int a = 0; a < 3; ++a) {
        const int mt = wm * 3 + a;
        const int ocb = mt * 16 + u * 4;
        float4 bi = *(const float4*)(bias + ocb);
        float bv[4] = {bi.x, bi.y, bi.z, bi.w};
        #pragma unroll
        for (int nt = 0; nt < 2; ++nt) {
            const int oh = oh0 + 2 * wn + nt;
            unsigned short* yb = ypb + (((size_t)img * OC + ocb) * OHH + oh) * OWW + ow0 + n;
            #pragma unroll
            for (int r = 0; r < 4; ++r)
                yb[(size_t)r * (OHH * OWW)] = f2bf(acc[a][nt][r] + bv[r]);
        }
    }
}

// ---------------- K3: LDS-free fused LCN + relu + maxpool (bf16 y input) --------------
__global__ __launch_bounds__(256) void lcn_pool_kernel(const unsigned short* __restrict__ y,
                                                       float* __restrict__ outp,
                                                       float* __restrict__ prep,
                                                       float* __restrict__ idxp) {
    const int tid   = threadIdx.x;
    const int band  = tid >> 6;
    const int lane  = tid & 63;
    const int plane = blockIdx.x;
    const int r0    = band * 28;
    const int c0    = lane * 2;
    const bool colv = (lane < 56);

    const unsigned short* yp = y + (size_t)plane * (OHH * OWW);
    float* pp  = prep + (size_t)plane * (OHH * OWW);
    float* op_ = outp + (size_t)plane * (56 * 56);
    float* ip_ = idxp + (size_t)plane * (56 * 56);

    const int lm = (lane + 63) & 63;
    const int lp = (lane + 1) & 63;

    float2 hs0{0,0}, hs1{0,0}, hs2{0,0}, hs3{0,0}, hs4{0,0};
    float2 q0{0,0},  q1{0,0},  q2{0,0},  q3{0,0},  q4{0,0};
    float2 y0{0,0},  y1{0,0},  y2{0,0};
    float2 ct0{0,0}, ct1{0,0}, ct2{0,0};
    float2 prev{0,0};

    #pragma unroll 1
    for (int i = 0; i < 36; ++i) {
        const int irow = r0 - 4 + i;
        float2 v = {0.f, 0.f};
        if ((unsigned)irow < OHH && colv) {
            unsigned int pr = *(const unsigned int*)(yp + irow * OWW + c0);
            v.x = __uint_as_float(pr << 16);
            v.y = __uint_as_float(pr & 0xffff0000u);
        }

        float Lx = __shfl(v.x, lm, 64), Ly = __shfl(v.y, lm, 64);
        float Rx = __shfl(v.x, lp, 64), Ry = __shfl(v.y, lp, 64);
        float2 hs_new;
        hs_new.x = Lx + Ly + v.x + v.y + Rx;
        hs_new.y = Ly + v.x + v.y + Rx + Ry;
        hs0 = hs1; hs1 = hs2; hs2 = hs3; hs3 = hs4; hs4 = hs_new;
        y0 = y1; y1 = y2; y2 = v;

        if (i >= 4) {
            const int m = irow - 2;
            float2 mean;
            mean.x = (hs0.x + hs1.x + hs2.x + hs3.x + hs4.x) * 0.04f;
            mean.y = (hs0.y + hs1.y + hs2.y + hs3.y + hs4.y) * 0.04f;
            float2 ct;
            ct.x = y0.x - mean.x;
            ct.y = y0.y - mean.y;
            if ((unsigned)m >= OHH || !colv) { ct.x = 0.f; ct.y = 0.f; }

            float cLx = __shfl(ct.x, lm, 64), cLy = __shfl(ct.y, lm, 64);
            float cRx = __shfl(ct.x, lp, 64), cRy = __shfl(ct.y, lp, 64);
            float2 q_new;
            q_new.x = cLx*cLx + cLy*cLy + ct.x*ct.x + ct.y*ct.y + cRx*cRx;
            q_new.y = cLy*cLy + ct.x*ct.x + ct.y*ct.y + cRx*cRx + cRy*cRy;
            q0 = q1; q1 = q2; q2 = q3; q3 = q4; q4 = q_new;
            ct0 = ct1; ct1 = ct2; ct2 = ct;

            if (i >= 8) {
                const int o = irow - 4;
                float2 var;
                var.x = (q0.x + q1.x + q2.x + q3.x + q4.x) * 0.04f;
                var.y = (q0.y + q1.y + q2.y + q3.y + q4.y) * 0.04f;
                float vx = fmaxf(ct0.x * rsqrtf(var.x + 1.0f), 0.f);
                float vy = fmaxf(ct0.y * rsqrtf(var.y + 1.0f), 0.f);
                if (colv) {
                    float2 pv = {vx, vy};
                    *(float2*)(pp + o * OWW + c0) = pv;
                }
                if (o & 1) {
                    float best = prev.x; int loc = 0;
                    if (prev.y > best) { best = prev.y; loc = 1; }
                    if (vx     > best) { best = vx;     loc = 2; }
                    if (vy     > best) { best = vy;     loc = 3; }
                    int idx = (o - 1 + (loc >> 1)) * OWW + (c0 + (loc & 1));
                    if (colv) {
                        size_t oo = (size_t)(o >> 1) * 56 + lane;
                        op_[oo] = best;
                        ip_[oo] = (float)idx;
                    }
                }
                prev.x = vx; prev.y = vy;
            }
        }
    }
}

extern "C" void kernel_launch(void* const* d_in, const int* in_sizes, int n_in,
                              void* d_out, int out_size, void* d_ws, size_t ws_size,
                              hipStream_t stream) {
    const float* x    = (const float*)d_in[0];
    const float* w    = (const float*)d_in[1];
    const float* bias = (const float*)d_in[2];

    unsigned short* y = (unsigned short*)d_ws;                  // 19,267,584 bf16 = 38.5 MB
    uint4* wfrag = (uint4*)((char*)d_ws + (size_t)NIMG * OC * OHH * OWW * 2);  // 36,864 B

    float* outp = (float*)d_out;                                // [16,96,56,56]
    float* prep = outp + (size_t)NIMG * OC * 56 * 56;           // [16,96,112,112]
    float* idxp = prep + (size_t)NIMG * OC * OHH * OWW;         // [16,96,56,56]

    wfrag_kernel<<<dim3(36), dim3(64), 0, stream>>>(w, wfrag);
    conv_mfma_kernel<<<dim3(98, NIMG), dim3(512), 0, stream>>>(x, wfrag, bias, y);
    lcn_pool_kernel<<<dim3(NIMG * OC), dim3(256), 0, stream>>>(y, outp, prep, idxp);
}